// Round 3
// baseline (2653.728 us; speedup 1.0000x reference)
//
#include <hip/hip_runtime.h>

// Viterbi decode (CRF): B=128, T=4096, L=64.
// Outputs: score[B] (f32), path[B][T] (written as float labels).
constexpr int kB = 128;
constexpr int kT = 4096;
constexpr int kL = 64;
constexpr int kSeg = 64;     // number of backtrace segments
constexpr int kSegLen = 64;  // rows per segment (last segment has 63)
constexpr float kNeg = -10000.0f;

// ---------------- K1A: forward, rotation formulation (plan A) ----------------
// Lane i owns output label i. delta kept in ONE register per lane; the
// all-to-all broadcast is 63 ds_bpermute rotations (precomputed addresses),
// paired with pre-rotated transitions trk[k] = trans[i][(i+k)&63].
// No LDS storage, no lgkmcnt(0) drains on the critical path.
__device__ __forceinline__ float step_rot(const float (&trk)[kL], const int (&adr)[kL],
                                          float d, float f) {
  const int di = __float_as_int(d);
#define ROT(k) (trk[k] + __int_as_float(__builtin_amdgcn_ds_bpermute(adr[k], di)))
  float a0 = trk[0] + d;
  float a1 = ROT(1);
  float a2 = ROT(2);
  float a3 = ROT(3);
#pragma unroll
  for (int k = 4; k < 60; k += 8) {
    // fmaxf(fmaxf(a,u),v) fuses to v_max3_f32
    a0 = fmaxf(fmaxf(a0, ROT(k + 0)), ROT(k + 1));
    a1 = fmaxf(fmaxf(a1, ROT(k + 2)), ROT(k + 3));
    a2 = fmaxf(fmaxf(a2, ROT(k + 4)), ROT(k + 5));
    a3 = fmaxf(fmaxf(a3, ROT(k + 6)), ROT(k + 7));
  }
  a0 = fmaxf(fmaxf(a0, ROT(60)), ROT(61));
  a1 = fmaxf(fmaxf(a1, ROT(62)), ROT(63));
#undef ROT
  return fmaxf(fmaxf(a0, a1), fmaxf(a2, a3)) + f;
}

__global__ __launch_bounds__(64) void fwd_delta(const float* __restrict__ feats,
                                                const float* __restrict__ trans,
                                                float* __restrict__ delta) {
  const int i = threadIdx.x;
  const int b = blockIdx.x;
  float trk[kL];
  int adr[kL];
#pragma unroll
  for (int k = 0; k < kL; ++k) {
    const int j = (i + k) & 63;
    trk[k] = trans[i * kL + j];  // scattered, init-only
    adr[k] = j * 4;              // bpermute byte address of source lane j
  }
  float d = (i == 62) ? 0.0f : kNeg;
  float* drow = delta + (size_t)b * kL + i;  // layout [T][B][L]
  *drow = d;
  drow += (size_t)kB * kL;
  const float* fb = feats + (size_t)b * kT * kL + i;
  // 4-deep feat prefetch ring
  float f0 = fb[(size_t)kL * 1], f1 = fb[(size_t)kL * 2];
  float f2 = fb[(size_t)kL * 3], f3 = fb[(size_t)kL * 4];
  int t = 1;
  for (int it = 0; it < 1023; ++it, t += 4) {
    d = step_rot(trk, adr, d, f0);
    *drow = d; drow += (size_t)kB * kL;
    f0 = fb[(size_t)kL * (t + 4 < kT ? t + 4 : kT - 1)];
    d = step_rot(trk, adr, d, f1);
    *drow = d; drow += (size_t)kB * kL;
    f1 = fb[(size_t)kL * (t + 5 < kT ? t + 5 : kT - 1)];
    d = step_rot(trk, adr, d, f2);
    *drow = d; drow += (size_t)kB * kL;
    f2 = fb[(size_t)kL * (t + 6 < kT ? t + 6 : kT - 1)];
    d = step_rot(trk, adr, d, f3);
    *drow = d; drow += (size_t)kB * kL;
    f3 = fb[(size_t)kL * (t + 7 < kT ? t + 7 : kT - 1)];
  }
  // tail: steps 4093, 4094, 4095
  d = step_rot(trk, adr, d, f0);
  *drow = d; drow += (size_t)kB * kL;
  d = step_rot(trk, adr, d, f1);
  *drow = d; drow += (size_t)kB * kL;
  d = step_rot(trk, adr, d, f2);
  *drow = d;
}

// ---------------- K1B: forward with argmax (plan B fallback) ----------------
__device__ __forceinline__ void step_b(const float (&tr)[kL], float2* dl2, int i,
                                       float fcur, unsigned char*& prow, float& dcur) {
  asm volatile("s_waitcnt lgkmcnt(0)" ::: "memory");
  float bA = -INFINITY, bBv = -INFINITY;
  int iA = 0, iB = 32;
#pragma unroll
  for (int p = 0; p < 16; ++p) {
    float2 q = dl2[p];
    float c0 = tr[2 * p] + q.x;
    bool g0 = c0 > bA; bA = g0 ? c0 : bA; iA = g0 ? 2 * p : iA;
    float c1 = tr[2 * p + 1] + q.y;
    bool g1 = c1 > bA; bA = g1 ? c1 : bA; iA = g1 ? 2 * p + 1 : iA;
  }
#pragma unroll
  for (int p = 16; p < 32; ++p) {
    float2 q = dl2[p];
    float c0 = tr[2 * p] + q.x;
    bool g0 = c0 > bBv; bBv = g0 ? c0 : bBv; iB = g0 ? 2 * p : iB;
    float c1 = tr[2 * p + 1] + q.y;
    bool g1 = c1 > bBv; bBv = g1 ? c1 : bBv; iB = g1 ? 2 * p + 1 : iB;
  }
  bool gm = bBv > bA;  // strict: tie keeps lower-j half
  float nd = (gm ? bBv : bA) + fcur;
  *prow = (unsigned char)(gm ? iB : iA);
  prow += (size_t)kB * kL;
  asm volatile("s_waitcnt lgkmcnt(0)" ::: "memory");
  reinterpret_cast<float*>(dl2)[i] = nd;
  dcur = nd;
}

__global__ __launch_bounds__(64) void fwd_psi(const float* __restrict__ feats,
                                              const float* __restrict__ trans,
                                              unsigned char* __restrict__ psi,
                                              float* __restrict__ dfin) {
  const int i = threadIdx.x;
  const int b = blockIdx.x;
  float tr[kL];
#pragma unroll
  for (int k = 0; k < kL; k += 4) {
    float4 v = *reinterpret_cast<const float4*>(trans + i * kL + k);
    tr[k] = v.x; tr[k + 1] = v.y; tr[k + 2] = v.z; tr[k + 3] = v.w;
  }
  __shared__ float2 dl2[kL / 2];
  const float d0 = (i == 62) ? 0.0f : kNeg;
  reinterpret_cast<float*>(dl2)[i] = d0;
  unsigned char* prow = psi + (size_t)b * kL + i;
  const float* fb = feats + (size_t)b * kT * kL + i;
  float dcur = d0;
  float f0 = fb[(size_t)kL * 1], f1 = fb[(size_t)kL * 2];
  float f2 = fb[(size_t)kL * 3], f3 = fb[(size_t)kL * 4];
  int t = 1;
  for (int it = 0; it < 1023; ++it, t += 4) {
    step_b(tr, dl2, i, f0, prow, dcur);
    f0 = fb[(size_t)kL * (t + 4 < kT ? t + 4 : kT - 1)];
    step_b(tr, dl2, i, f1, prow, dcur);
    f1 = fb[(size_t)kL * (t + 5 < kT ? t + 5 : kT - 1)];
    step_b(tr, dl2, i, f2, prow, dcur);
    f2 = fb[(size_t)kL * (t + 6 < kT ? t + 6 : kT - 1)];
    step_b(tr, dl2, i, f3, prow, dcur);
    f3 = fb[(size_t)kL * (t + 7 < kT ? t + 7 : kT - 1)];
  }
  step_b(tr, dl2, i, f0, prow, dcur);
  step_b(tr, dl2, i, f1, prow, dcur);
  step_b(tr, dl2, i, f2, prow, dcur);
  dfin[(size_t)b * kL + i] = dcur;
}

// ---------------- K2: recompute backpointers from stored delta (plan A) ------
// row r = t*128 + b; delta layout [T][B][L] makes row base = delta + r*64.
__global__ __launch_bounds__(256) void psi_from_delta(const float* __restrict__ delta,
                                                      const float* __restrict__ trans,
                                                      unsigned char* __restrict__ psi) {
  const int lane = threadIdx.x & 63;
  const int w = __builtin_amdgcn_readfirstlane(blockIdx.x * 4 + (threadIdx.x >> 6));
  float tr[kL];
#pragma unroll
  for (int k = 0; k < kL; k += 4) {
    float4 v = *reinterpret_cast<const float4*>(trans + lane * kL + k);
    tr[k] = v.x; tr[k + 1] = v.y; tr[k + 2] = v.z; tr[k + 3] = v.w;
  }
  const int r0 = w * 8;  // 8 rows per wave; grid sized exactly
  for (int rr = 0; rr < 8; ++rr) {
    const int r = r0 + rr;
    const float4* row4 = reinterpret_cast<const float4*>(delta + (size_t)r * kL);
    float bA = -INFINITY, bBv = -INFINITY;
    int iA = 0, iB = 32;
#pragma unroll
    for (int q = 0; q < 8; ++q) {
      float4 dv = row4[q];
      float c; bool g;
      c = tr[4 * q + 0] + dv.x; g = c > bA; bA = g ? c : bA; iA = g ? 4 * q + 0 : iA;
      c = tr[4 * q + 1] + dv.y; g = c > bA; bA = g ? c : bA; iA = g ? 4 * q + 1 : iA;
      c = tr[4 * q + 2] + dv.z; g = c > bA; bA = g ? c : bA; iA = g ? 4 * q + 2 : iA;
      c = tr[4 * q + 3] + dv.w; g = c > bA; bA = g ? c : bA; iA = g ? 4 * q + 3 : iA;
    }
#pragma unroll
    for (int q = 8; q < 16; ++q) {
      float4 dv = row4[q];
      float c; bool g;
      c = tr[4 * q + 0] + dv.x; g = c > bBv; bBv = g ? c : bBv; iB = g ? 4 * q + 0 : iB;
      c = tr[4 * q + 1] + dv.y; g = c > bBv; bBv = g ? c : bBv; iB = g ? 4 * q + 1 : iB;
      c = tr[4 * q + 2] + dv.z; g = c > bBv; bBv = g ? c : bBv; iB = g ? 4 * q + 2 : iB;
      c = tr[4 * q + 3] + dv.w; g = c > bBv; bBv = g ? c : bBv; iB = g ? 4 * q + 3 : iB;
    }
    bool gm = bBv > bA;  // tie -> lower half (first occurrence)
    psi[(size_t)r * kL + lane] = (unsigned char)(gm ? iB : iA);
  }
}

// ---------------- K3: segment composition (in-place psi -> M) ----------------
__global__ __launch_bounds__(256) void seg_compose(unsigned char* psiM,
                                                   unsigned char* __restrict__ C) {
  const int lane = threadIdx.x & 63;
  const int w = blockIdx.x * 4 + (threadIdx.x >> 6);
  const int s = w >> 7;
  const int b = w & 127;
  const int tstart = s * kSegLen;
  const int tend = (tstart + kSegLen < kT) ? tstart + kSegLen : kT - 1;  // last seg: 4095
  const size_t stride = (size_t)kB * kL;
  size_t off = ((size_t)(tend - 1) * kB + b) * kL + lane;
  int m = lane;
  int v = psiM[off];
  for (int t = tend - 1; t > tstart; --t) {
    int vn = psiM[off - stride];          // prefetch next row
    m = __shfl(v, m, 64);                 // m = psi_row[m]
    psiM[off] = (unsigned char)m;         // M[t][b][e] = path[t] | hyp e
    v = vn;
    off -= stride;
  }
  m = __shfl(v, m, 64);
  psiM[off] = (unsigned char)m;
  C[((size_t)s * kB + b) * kL + lane] = (unsigned char)m;  // composed map
}

// ---------------- K4: score, last label, boundary-label scan ----------------
__global__ __launch_bounds__(64) void score_scan(const float* __restrict__ dfin,
                                                 const unsigned char* __restrict__ C,
                                                 int* __restrict__ E,
                                                 float* __restrict__ out) {
  const int b = blockIdx.x;
  const int i = threadIdx.x;
  float d = dfin[(size_t)b * kL + i];
  float m = d;
#pragma unroll
  for (int off = 32; off; off >>= 1) m = fmaxf(m, __shfl_xor(m, off, 64));
  unsigned long long msk = __ballot(d == m);
  int ll = __ffsll(msk) - 1;  // first (lowest) argmax lane
  if (i == 0) {
    out[b] = m;
    out[kB + (size_t)b * kT + (kT - 1)] = (float)ll;
    int lbl = ll;
    for (int s = kSeg - 1; s >= 0; --s) {
      E[s * kB + b] = lbl;                              // label at t_end(s)
      lbl = C[((size_t)s * kB + b) * kL + lbl];         // -> label at t_start(s)
    }
  }
}

// ---------------- K5: parallel path gather ----------------
__global__ __launch_bounds__(256) void path_fill(const unsigned char* __restrict__ M,
                                                 const int* __restrict__ E,
                                                 float* __restrict__ out) {
  const int n = blockIdx.x * 256 + threadIdx.x;  // n = b*4096 + t
  const int b = n >> 12;
  const int t = n & (kT - 1);
  if (t == kT - 1) return;  // written by score_scan
  const int e = E[(t >> 6) * kB + b];
  const unsigned char lab = M[((size_t)t * kB + b) * kL + e];
  out[kB + (size_t)b * kT + t] = (float)lab;
}

extern "C" void kernel_launch(void* const* d_in, const int* in_sizes, int n_in,
                              void* d_out, int out_size, void* d_ws, size_t ws_size,
                              hipStream_t stream) {
  const float* feats = (const float*)d_in[0];
  const float* trans = (const float*)d_in[1];
  float* out = (float*)d_out;
  char* ws = (char*)d_ws;

  const size_t deltaB = (size_t)kT * kB * kL * 4;   // 134,217,728
  const size_t psiB   = (size_t)kT * kB * kL;       //  33,554,432
  const size_t CBy    = (size_t)kSeg * kB * kL;     //     524,288
  const size_t EBy    = (size_t)kSeg * kB * 4;      //      32,768

  if (ws_size >= deltaB + psiB + CBy + EBy) {
    // Plan A: value-only forward + fully-parallel backpointer recompute.
    float* delta = (float*)ws;
    unsigned char* psi = (unsigned char*)(ws + deltaB);
    unsigned char* C = (unsigned char*)(ws + deltaB + psiB);
    int* E = (int*)(ws + deltaB + psiB + CBy);
    hipLaunchKernelGGL(fwd_delta, dim3(kB), dim3(64), 0, stream, feats, trans, delta);
    hipLaunchKernelGGL(psi_from_delta, dim3(16380), dim3(256), 0, stream, delta, trans, psi);
    hipLaunchKernelGGL(seg_compose, dim3(2048), dim3(256), 0, stream, psi, C);
    hipLaunchKernelGGL(score_scan, dim3(kB), dim3(64), 0, stream,
                       delta + (size_t)(kT - 1) * kB * kL, C, E, out);
    hipLaunchKernelGGL(path_fill, dim3(2048), dim3(256), 0, stream, psi, E, out);
  } else {
    // Plan B: argmax in forward (psi only, ~34 MB workspace).
    unsigned char* psi = (unsigned char*)ws;
    unsigned char* C = (unsigned char*)(ws + psiB);
    int* E = (int*)(ws + psiB + CBy);
    float* dfin = (float*)(ws + psiB + CBy + EBy);
    hipLaunchKernelGGL(fwd_psi, dim3(kB), dim3(64), 0, stream, feats, trans, psi, dfin);
    hipLaunchKernelGGL(seg_compose, dim3(2048), dim3(256), 0, stream, psi, C);
    hipLaunchKernelGGL(score_scan, dim3(kB), dim3(64), 0, stream, dfin, C, E, out);
    hipLaunchKernelGGL(path_fill, dim3(2048), dim3(256), 0, stream, psi, E, out);
  }
}

// Round 4
// 2347.360 us; speedup vs baseline: 1.1305x; 1.1305x over previous
//
#include <hip/hip_runtime.h>

// Viterbi decode (CRF): B=128, T=4096, L=64.
// Outputs: score[B] (f32), path[B][T] (written as float labels).
constexpr int kB = 128;
constexpr int kT = 4096;
constexpr int kL = 64;
constexpr int kSeg = 64;     // number of backtrace segments
constexpr int kSegLen = 64;  // rows per segment (last segment has 63)
constexpr float kNeg = -10000.0f;

typedef float f32x2 __attribute__((ext_vector_type(2)));

// ---------------- K1A forward step: single-buffer LDS broadcast --------------
// One wave per batch; lane i owns output label i. delta published via ONE
// ds_write_b32 then read back as 16 uniform-address ds_read_b128 broadcasts.
// Single wave + in-order DS pipe => no barriers, no lgkmcnt(0) drains; the
// compiler emits counted lgkmcnt before each read's first use. Adds paired as
// float2 to select v_pk_add_f32 (two IEEE f32 adds, bitwise exact).
__device__ __forceinline__ float step_lds(const f32x2 (&tr2)[kL / 2], float* dl,
                                          const float4* dl4, int i, float d, float f) {
  asm volatile("" ::: "memory");
  dl[i] = d;                       // publish delta(t-1); FIFO orders before reads
  asm volatile("" ::: "memory");
  float m[16];
#pragma unroll
  for (int q = 0; q < 16; ++q) {
    float4 v = dl4[q];             // uniform-address broadcast read (b128)
    f32x2 lo, hi;
    lo.x = v.x; lo.y = v.y; hi.x = v.z; hi.y = v.w;
    f32x2 p = tr2[2 * q] + lo;     // v_pk_add_f32
    f32x2 r = tr2[2 * q + 1] + hi;
    m[q] = fmaxf(fmaxf(p.x, p.y), fmaxf(r.x, r.y));
  }
#pragma unroll
  for (int s = 8; s; s >>= 1)
    for (int q = 0; q < s; ++q) m[q] = fmaxf(m[q], m[q + s]);
  return m[0] + f;
}

__global__ __launch_bounds__(64) void fwd_delta(const float* __restrict__ feats,
                                                const float* __restrict__ trans,
                                                float* __restrict__ delta) {
  const int i = threadIdx.x;
  const int b = blockIdx.x;
  f32x2 tr2[kL / 2];
#pragma unroll
  for (int k = 0; k < kL; k += 4) {
    float4 v = *reinterpret_cast<const float4*>(trans + i * kL + k);
    tr2[k / 2].x = v.x; tr2[k / 2].y = v.y;
    tr2[k / 2 + 1].x = v.z; tr2[k / 2 + 1].y = v.w;
  }
  __shared__ float dl[kL];
  const float4* dl4 = reinterpret_cast<const float4*>(dl);
  float d = (i == 62) ? 0.0f : kNeg;
  float* drow = delta + (size_t)b * kL + i;  // layout [T][B][L]
  *drow = d;
  drow += (size_t)kB * kL;
  const float* fb = feats + (size_t)b * kT * kL + i;
  // 4-deep feat prefetch ring
  float f0 = fb[(size_t)kL * 1], f1 = fb[(size_t)kL * 2];
  float f2 = fb[(size_t)kL * 3], f3 = fb[(size_t)kL * 4];
  int t = 1;
  for (int it = 0; it < 1023; ++it, t += 4) {
    d = step_lds(tr2, dl, dl4, i, d, f0);
    *drow = d; drow += (size_t)kB * kL;
    f0 = fb[(size_t)kL * (t + 4 < kT ? t + 4 : kT - 1)];
    d = step_lds(tr2, dl, dl4, i, d, f1);
    *drow = d; drow += (size_t)kB * kL;
    f1 = fb[(size_t)kL * (t + 5 < kT ? t + 5 : kT - 1)];
    d = step_lds(tr2, dl, dl4, i, d, f2);
    *drow = d; drow += (size_t)kB * kL;
    f2 = fb[(size_t)kL * (t + 6 < kT ? t + 6 : kT - 1)];
    d = step_lds(tr2, dl, dl4, i, d, f3);
    *drow = d; drow += (size_t)kB * kL;
    f3 = fb[(size_t)kL * (t + 7 < kT ? t + 7 : kT - 1)];
  }
  // tail: steps 4093, 4094, 4095
  d = step_lds(tr2, dl, dl4, i, d, f0);
  *drow = d; drow += (size_t)kB * kL;
  d = step_lds(tr2, dl, dl4, i, d, f1);
  *drow = d; drow += (size_t)kB * kL;
  d = step_lds(tr2, dl, dl4, i, d, f2);
  *drow = d;
}

// ---------------- K1B: forward with argmax (plan B fallback) ----------------
__device__ __forceinline__ void step_b(const float (&tr)[kL], float2* dl2, int i,
                                       float fcur, unsigned char*& prow, float& dcur) {
  asm volatile("s_waitcnt lgkmcnt(0)" ::: "memory");
  float bA = -INFINITY, bBv = -INFINITY;
  int iA = 0, iB = 32;
#pragma unroll
  for (int p = 0; p < 16; ++p) {
    float2 q = dl2[p];
    float c0 = tr[2 * p] + q.x;
    bool g0 = c0 > bA; bA = g0 ? c0 : bA; iA = g0 ? 2 * p : iA;
    float c1 = tr[2 * p + 1] + q.y;
    bool g1 = c1 > bA; bA = g1 ? c1 : bA; iA = g1 ? 2 * p + 1 : iA;
  }
#pragma unroll
  for (int p = 16; p < 32; ++p) {
    float2 q = dl2[p];
    float c0 = tr[2 * p] + q.x;
    bool g0 = c0 > bBv; bBv = g0 ? c0 : bBv; iB = g0 ? 2 * p : iB;
    float c1 = tr[2 * p + 1] + q.y;
    bool g1 = c1 > bBv; bBv = g1 ? c1 : bBv; iB = g1 ? 2 * p + 1 : iB;
  }
  bool gm = bBv > bA;  // strict: tie keeps lower-j half
  float nd = (gm ? bBv : bA) + fcur;
  *prow = (unsigned char)(gm ? iB : iA);
  prow += (size_t)kB * kL;
  asm volatile("s_waitcnt lgkmcnt(0)" ::: "memory");
  reinterpret_cast<float*>(dl2)[i] = nd;
  dcur = nd;
}

__global__ __launch_bounds__(64) void fwd_psi(const float* __restrict__ feats,
                                              const float* __restrict__ trans,
                                              unsigned char* __restrict__ psi,
                                              float* __restrict__ dfin) {
  const int i = threadIdx.x;
  const int b = blockIdx.x;
  float tr[kL];
#pragma unroll
  for (int k = 0; k < kL; k += 4) {
    float4 v = *reinterpret_cast<const float4*>(trans + i * kL + k);
    tr[k] = v.x; tr[k + 1] = v.y; tr[k + 2] = v.z; tr[k + 3] = v.w;
  }
  __shared__ float2 dl2[kL / 2];
  const float d0 = (i == 62) ? 0.0f : kNeg;
  reinterpret_cast<float*>(dl2)[i] = d0;
  unsigned char* prow = psi + (size_t)b * kL + i;
  const float* fb = feats + (size_t)b * kT * kL + i;
  float dcur = d0;
  float f0 = fb[(size_t)kL * 1], f1 = fb[(size_t)kL * 2];
  float f2 = fb[(size_t)kL * 3], f3 = fb[(size_t)kL * 4];
  int t = 1;
  for (int it = 0; it < 1023; ++it, t += 4) {
    step_b(tr, dl2, i, f0, prow, dcur);
    f0 = fb[(size_t)kL * (t + 4 < kT ? t + 4 : kT - 1)];
    step_b(tr, dl2, i, f1, prow, dcur);
    f1 = fb[(size_t)kL * (t + 5 < kT ? t + 5 : kT - 1)];
    step_b(tr, dl2, i, f2, prow, dcur);
    f2 = fb[(size_t)kL * (t + 6 < kT ? t + 6 : kT - 1)];
    step_b(tr, dl2, i, f3, prow, dcur);
    f3 = fb[(size_t)kL * (t + 7 < kT ? t + 7 : kT - 1)];
  }
  step_b(tr, dl2, i, f0, prow, dcur);
  step_b(tr, dl2, i, f1, prow, dcur);
  step_b(tr, dl2, i, f2, prow, dcur);
  dfin[(size_t)b * kL + i] = dcur;
}

// ---------------- K2: recompute backpointers from stored delta (plan A) ------
// row r = t*128 + b; delta layout [T][B][L] makes row base = delta + r*64.
__global__ __launch_bounds__(256) void psi_from_delta(const float* __restrict__ delta,
                                                      const float* __restrict__ trans,
                                                      unsigned char* __restrict__ psi) {
  const int lane = threadIdx.x & 63;
  const int w = __builtin_amdgcn_readfirstlane(blockIdx.x * 4 + (threadIdx.x >> 6));
  float tr[kL];
#pragma unroll
  for (int k = 0; k < kL; k += 4) {
    float4 v = *reinterpret_cast<const float4*>(trans + lane * kL + k);
    tr[k] = v.x; tr[k + 1] = v.y; tr[k + 2] = v.z; tr[k + 3] = v.w;
  }
  const int r0 = w * 8;  // 8 rows per wave; grid sized exactly
  for (int rr = 0; rr < 8; ++rr) {
    const int r = r0 + rr;
    const float4* row4 = reinterpret_cast<const float4*>(delta + (size_t)r * kL);
    float bA = -INFINITY, bBv = -INFINITY;
    int iA = 0, iB = 32;
#pragma unroll
    for (int q = 0; q < 8; ++q) {
      float4 dv = row4[q];
      float c; bool g;
      c = tr[4 * q + 0] + dv.x; g = c > bA; bA = g ? c : bA; iA = g ? 4 * q + 0 : iA;
      c = tr[4 * q + 1] + dv.y; g = c > bA; bA = g ? c : bA; iA = g ? 4 * q + 1 : iA;
      c = tr[4 * q + 2] + dv.z; g = c > bA; bA = g ? c : bA; iA = g ? 4 * q + 2 : iA;
      c = tr[4 * q + 3] + dv.w; g = c > bA; bA = g ? c : bA; iA = g ? 4 * q + 3 : iA;
    }
#pragma unroll
    for (int q = 8; q < 16; ++q) {
      float4 dv = row4[q];
      float c; bool g;
      c = tr[4 * q + 0] + dv.x; g = c > bBv; bBv = g ? c : bBv; iB = g ? 4 * q + 0 : iB;
      c = tr[4 * q + 1] + dv.y; g = c > bBv; bBv = g ? c : bBv; iB = g ? 4 * q + 1 : iB;
      c = tr[4 * q + 2] + dv.z; g = c > bBv; bBv = g ? c : bBv; iB = g ? 4 * q + 2 : iB;
      c = tr[4 * q + 3] + dv.w; g = c > bBv; bBv = g ? c : bBv; iB = g ? 4 * q + 3 : iB;
    }
    bool gm = bBv > bA;  // tie -> lower half (first occurrence)
    psi[(size_t)r * kL + lane] = (unsigned char)(gm ? iB : iA);
  }
}

// ---------------- K3: segment composition (in-place psi -> M) ----------------
__global__ __launch_bounds__(256) void seg_compose(unsigned char* psiM,
                                                   unsigned char* __restrict__ C) {
  const int lane = threadIdx.x & 63;
  const int w = blockIdx.x * 4 + (threadIdx.x >> 6);
  const int s = w >> 7;
  const int b = w & 127;
  const int tstart = s * kSegLen;
  const int tend = (tstart + kSegLen < kT) ? tstart + kSegLen : kT - 1;  // last seg: 4095
  const size_t stride = (size_t)kB * kL;
  size_t off = ((size_t)(tend - 1) * kB + b) * kL + lane;
  int m = lane;
  int v = psiM[off];
  for (int t = tend - 1; t > tstart; --t) {
    int vn = psiM[off - stride];          // prefetch next row
    m = __shfl(v, m, 64);                 // m = psi_row[m]
    psiM[off] = (unsigned char)m;         // M[t][b][e] = path[t] | hyp e
    v = vn;
    off -= stride;
  }
  m = __shfl(v, m, 64);
  psiM[off] = (unsigned char)m;
  C[((size_t)s * kB + b) * kL + lane] = (unsigned char)m;  // composed map
}

// ---------------- K4: score, last label, boundary-label scan ----------------
__global__ __launch_bounds__(64) void score_scan(const float* __restrict__ dfin,
                                                 const unsigned char* __restrict__ C,
                                                 int* __restrict__ E,
                                                 float* __restrict__ out) {
  const int b = blockIdx.x;
  const int i = threadIdx.x;
  float d = dfin[(size_t)b * kL + i];
  float m = d;
#pragma unroll
  for (int off = 32; off; off >>= 1) m = fmaxf(m, __shfl_xor(m, off, 64));
  unsigned long long msk = __ballot(d == m);
  int ll = __ffsll(msk) - 1;  // first (lowest) argmax lane
  if (i == 0) {
    out[b] = m;
    out[kB + (size_t)b * kT + (kT - 1)] = (float)ll;
    int lbl = ll;
    for (int s = kSeg - 1; s >= 0; --s) {
      E[s * kB + b] = lbl;                              // label at t_end(s)
      lbl = C[((size_t)s * kB + b) * kL + lbl];         // -> label at t_start(s)
    }
  }
}

// ---------------- K5: parallel path gather ----------------
__global__ __launch_bounds__(256) void path_fill(const unsigned char* __restrict__ M,
                                                 const int* __restrict__ E,
                                                 float* __restrict__ out) {
  const int n = blockIdx.x * 256 + threadIdx.x;  // n = b*4096 + t
  const int b = n >> 12;
  const int t = n & (kT - 1);
  if (t == kT - 1) return;  // written by score_scan
  const int e = E[(t >> 6) * kB + b];
  const unsigned char lab = M[((size_t)t * kB + b) * kL + e];
  out[kB + (size_t)b * kT + t] = (float)lab;
}

extern "C" void kernel_launch(void* const* d_in, const int* in_sizes, int n_in,
                              void* d_out, int out_size, void* d_ws, size_t ws_size,
                              hipStream_t stream) {
  const float* feats = (const float*)d_in[0];
  const float* trans = (const float*)d_in[1];
  float* out = (float*)d_out;
  char* ws = (char*)d_ws;

  const size_t deltaB = (size_t)kT * kB * kL * 4;   // 134,217,728
  const size_t psiB   = (size_t)kT * kB * kL;       //  33,554,432
  const size_t CBy    = (size_t)kSeg * kB * kL;     //     524,288
  const size_t EBy    = (size_t)kSeg * kB * 4;      //      32,768

  if (ws_size >= deltaB + psiB + CBy + EBy) {
    // Plan A: value-only forward + fully-parallel backpointer recompute.
    float* delta = (float*)ws;
    unsigned char* psi = (unsigned char*)(ws + deltaB);
    unsigned char* C = (unsigned char*)(ws + deltaB + psiB);
    int* E = (int*)(ws + deltaB + psiB + CBy);
    hipLaunchKernelGGL(fwd_delta, dim3(kB), dim3(64), 0, stream, feats, trans, delta);
    hipLaunchKernelGGL(psi_from_delta, dim3(16380), dim3(256), 0, stream, delta, trans, psi);
    hipLaunchKernelGGL(seg_compose, dim3(2048), dim3(256), 0, stream, psi, C);
    hipLaunchKernelGGL(score_scan, dim3(kB), dim3(64), 0, stream,
                       delta + (size_t)(kT - 1) * kB * kL, C, E, out);
    hipLaunchKernelGGL(path_fill, dim3(2048), dim3(256), 0, stream, psi, E, out);
  } else {
    // Plan B: argmax in forward (psi only, ~34 MB workspace).
    unsigned char* psi = (unsigned char*)ws;
    unsigned char* C = (unsigned char*)(ws + psiB);
    int* E = (int*)(ws + psiB + CBy);
    float* dfin = (float*)(ws + psiB + CBy + EBy);
    hipLaunchKernelGGL(fwd_psi, dim3(kB), dim3(64), 0, stream, feats, trans, psi, dfin);
    hipLaunchKernelGGL(seg_compose, dim3(2048), dim3(256), 0, stream, psi, C);
    hipLaunchKernelGGL(score_scan, dim3(kB), dim3(64), 0, stream, dfin, C, E, out);
    hipLaunchKernelGGL(path_fill, dim3(2048), dim3(256), 0, stream, psi, E, out);
  }
}

// Round 5
// 1374.318 us; speedup vs baseline: 1.9309x; 1.7080x over previous
//
#include <hip/hip_runtime.h>

// Viterbi decode (CRF): B=128, T=4096, L=64.
// Outputs: score[B] (f32), path[B][T] (written as float labels).
constexpr int kB = 128;
constexpr int kT = 4096;
constexpr int kL = 64;
constexpr int kSeg = 64;     // number of backtrace segments
constexpr int kSegLen = 64;  // rows per segment (last segment has 63)
constexpr float kNeg = -10000.0f;

typedef float f32x2 __attribute__((ext_vector_type(2)));

// ---------------- K1A forward step: single-buffer LDS broadcast --------------
// One wave per batch; lane i owns output label i. delta published via ONE
// ds_write_b32 then read back as 16 uniform-address ds_read_b128 broadcasts.
// ALL 16 reads are materialized into registers first (needs ~64 spare VGPRs —
// hence __launch_bounds__(64,1)) so the compiler issues them back-to-back and
// we pay a single LDS round-trip per step, not 4-6.
__device__ __forceinline__ float step_lds(const f32x2 (&tr2)[kL / 2], float* dl,
                                          const float4* dl4, int i, float d, float f) {
  asm volatile("" ::: "memory");
  dl[i] = d;                       // publish delta(t-1); in-order DS pipe
  asm volatile("" ::: "memory");
  float4 v[16];
#pragma unroll
  for (int q = 0; q < 16; ++q) v[q] = dl4[q];  // 16x ds_read_b128, batched
  float m[16];
#pragma unroll
  for (int q = 0; q < 16; ++q) {
    f32x2 lo, hi;
    lo.x = v[q].x; lo.y = v[q].y; hi.x = v[q].z; hi.y = v[q].w;
    f32x2 p = tr2[2 * q] + lo;     // v_pk_add_f32
    f32x2 r = tr2[2 * q + 1] + hi;
    m[q] = fmaxf(fmaxf(p.x, p.y), fmaxf(r.x, r.y));
  }
#pragma unroll
  for (int s = 8; s; s >>= 1)
    for (int q = 0; q < s; ++q) m[q] = fmaxf(m[q], m[q + s]);
  return m[0] + f;
}

__global__ __launch_bounds__(64, 1) void fwd_delta(const float* __restrict__ feats,
                                                   const float* __restrict__ trans,
                                                   float* __restrict__ delta) {
  const int i = threadIdx.x;
  const int b = blockIdx.x;
  const size_t kBL = (size_t)kB * kL;
  f32x2 tr2[kL / 2];
#pragma unroll
  for (int k = 0; k < kL; k += 4) {
    float4 v = *reinterpret_cast<const float4*>(trans + i * kL + k);
    tr2[k / 2].x = v.x; tr2[k / 2].y = v.y;
    tr2[k / 2 + 1].x = v.z; tr2[k / 2 + 1].y = v.w;
  }
  __shared__ float dl[kL];
  const float4* dl4 = reinterpret_cast<const float4*>(dl);
  float d = (i == 62) ? 0.0f : kNeg;
  float* drow = delta + kBL * 0 + (size_t)b * kL + i;  // layout [T][B][L]
  *drow = d;
  drow += kBL;
  const float* fp = feats + (size_t)b * kT * kL + i;
  // 4-deep feat prefetch ring; no clamping in the main loop.
  float f0 = fp[64 * 1], f1 = fp[64 * 2], f2 = fp[64 * 3], f3 = fp[64 * 4];
  const float* pf = fp + 64 * 5;
  for (int it = 0; it < 1022; ++it) {
    d = step_lds(tr2, dl, dl4, i, d, f0);
    *drow = d; drow += kBL; f0 = pf[0];
    d = step_lds(tr2, dl, dl4, i, d, f1);
    *drow = d; drow += kBL; f1 = pf[64];
    d = step_lds(tr2, dl, dl4, i, d, f2);
    *drow = d; drow += kBL; f2 = pf[128];
    d = step_lds(tr2, dl, dl4, i, d, f3);
    *drow = d; drow += kBL; f3 = pf[192];
    pf += 256;
  }
  // pf now points at row t=4093. Steps remaining: 4089..4095 (7 steps).
  float g0 = pf[0], g1 = pf[64], g2 = pf[128];
  d = step_lds(tr2, dl, dl4, i, d, f0); *drow = d; drow += kBL;
  d = step_lds(tr2, dl, dl4, i, d, f1); *drow = d; drow += kBL;
  d = step_lds(tr2, dl, dl4, i, d, f2); *drow = d; drow += kBL;
  d = step_lds(tr2, dl, dl4, i, d, f3); *drow = d; drow += kBL;
  d = step_lds(tr2, dl, dl4, i, d, g0); *drow = d; drow += kBL;
  d = step_lds(tr2, dl, dl4, i, d, g1); *drow = d; drow += kBL;
  d = step_lds(tr2, dl, dl4, i, d, g2); *drow = d;
}

// ---------------- K1B: forward with argmax (plan B fallback) ----------------
__device__ __forceinline__ void step_b(const float (&tr)[kL], float2* dl2, int i,
                                       float fcur, unsigned char*& prow, float& dcur) {
  asm volatile("s_waitcnt lgkmcnt(0)" ::: "memory");
  float bA = -INFINITY, bBv = -INFINITY;
  int iA = 0, iB = 32;
#pragma unroll
  for (int p = 0; p < 16; ++p) {
    float2 q = dl2[p];
    float c0 = tr[2 * p] + q.x;
    bool g0 = c0 > bA; bA = g0 ? c0 : bA; iA = g0 ? 2 * p : iA;
    float c1 = tr[2 * p + 1] + q.y;
    bool g1 = c1 > bA; bA = g1 ? c1 : bA; iA = g1 ? 2 * p + 1 : iA;
  }
#pragma unroll
  for (int p = 16; p < 32; ++p) {
    float2 q = dl2[p];
    float c0 = tr[2 * p] + q.x;
    bool g0 = c0 > bBv; bBv = g0 ? c0 : bBv; iB = g0 ? 2 * p : iB;
    float c1 = tr[2 * p + 1] + q.y;
    bool g1 = c1 > bBv; bBv = g1 ? c1 : bBv; iB = g1 ? 2 * p + 1 : iB;
  }
  bool gm = bBv > bA;  // strict: tie keeps lower-j half
  float nd = (gm ? bBv : bA) + fcur;
  *prow = (unsigned char)(gm ? iB : iA);
  prow += (size_t)kB * kL;
  asm volatile("s_waitcnt lgkmcnt(0)" ::: "memory");
  reinterpret_cast<float*>(dl2)[i] = nd;
  dcur = nd;
}

__global__ __launch_bounds__(64) void fwd_psi(const float* __restrict__ feats,
                                              const float* __restrict__ trans,
                                              unsigned char* __restrict__ psi,
                                              float* __restrict__ dfin) {
  const int i = threadIdx.x;
  const int b = blockIdx.x;
  float tr[kL];
#pragma unroll
  for (int k = 0; k < kL; k += 4) {
    float4 v = *reinterpret_cast<const float4*>(trans + i * kL + k);
    tr[k] = v.x; tr[k + 1] = v.y; tr[k + 2] = v.z; tr[k + 3] = v.w;
  }
  __shared__ float2 dl2[kL / 2];
  const float d0 = (i == 62) ? 0.0f : kNeg;
  reinterpret_cast<float*>(dl2)[i] = d0;
  unsigned char* prow = psi + (size_t)b * kL + i;
  const float* fb = feats + (size_t)b * kT * kL + i;
  float dcur = d0;
  float f0 = fb[(size_t)kL * 1], f1 = fb[(size_t)kL * 2];
  float f2 = fb[(size_t)kL * 3], f3 = fb[(size_t)kL * 4];
  int t = 1;
  for (int it = 0; it < 1023; ++it, t += 4) {
    step_b(tr, dl2, i, f0, prow, dcur);
    f0 = fb[(size_t)kL * (t + 4 < kT ? t + 4 : kT - 1)];
    step_b(tr, dl2, i, f1, prow, dcur);
    f1 = fb[(size_t)kL * (t + 5 < kT ? t + 5 : kT - 1)];
    step_b(tr, dl2, i, f2, prow, dcur);
    f2 = fb[(size_t)kL * (t + 6 < kT ? t + 6 : kT - 1)];
    step_b(tr, dl2, i, f3, prow, dcur);
    f3 = fb[(size_t)kL * (t + 7 < kT ? t + 7 : kT - 1)];
  }
  step_b(tr, dl2, i, f0, prow, dcur);
  step_b(tr, dl2, i, f1, prow, dcur);
  step_b(tr, dl2, i, f2, prow, dcur);
  dfin[(size_t)b * kL + i] = dcur;
}

// ---------------- K2: recompute backpointers from stored delta (plan A) ------
// row r = t*128 + b; delta layout [T][B][L] makes row base = delta + r*64.
__global__ __launch_bounds__(256) void psi_from_delta(const float* __restrict__ delta,
                                                      const float* __restrict__ trans,
                                                      unsigned char* __restrict__ psi) {
  const int lane = threadIdx.x & 63;
  const int w = __builtin_amdgcn_readfirstlane(blockIdx.x * 4 + (threadIdx.x >> 6));
  float tr[kL];
#pragma unroll
  for (int k = 0; k < kL; k += 4) {
    float4 v = *reinterpret_cast<const float4*>(trans + lane * kL + k);
    tr[k] = v.x; tr[k + 1] = v.y; tr[k + 2] = v.z; tr[k + 3] = v.w;
  }
  const int r0 = w * 8;  // 8 rows per wave; grid sized exactly
  for (int rr = 0; rr < 8; ++rr) {
    const int r = r0 + rr;
    const float4* row4 = reinterpret_cast<const float4*>(delta + (size_t)r * kL);
    float bA = -INFINITY, bBv = -INFINITY;
    int iA = 0, iB = 32;
#pragma unroll
    for (int q = 0; q < 8; ++q) {
      float4 dv = row4[q];
      float c; bool g;
      c = tr[4 * q + 0] + dv.x; g = c > bA; bA = g ? c : bA; iA = g ? 4 * q + 0 : iA;
      c = tr[4 * q + 1] + dv.y; g = c > bA; bA = g ? c : bA; iA = g ? 4 * q + 1 : iA;
      c = tr[4 * q + 2] + dv.z; g = c > bA; bA = g ? c : bA; iA = g ? 4 * q + 2 : iA;
      c = tr[4 * q + 3] + dv.w; g = c > bA; bA = g ? c : bA; iA = g ? 4 * q + 3 : iA;
    }
#pragma unroll
    for (int q = 8; q < 16; ++q) {
      float4 dv = row4[q];
      float c; bool g;
      c = tr[4 * q + 0] + dv.x; g = c > bBv; bBv = g ? c : bBv; iB = g ? 4 * q + 0 : iB;
      c = tr[4 * q + 1] + dv.y; g = c > bBv; bBv = g ? c : bBv; iB = g ? 4 * q + 1 : iB;
      c = tr[4 * q + 2] + dv.z; g = c > bBv; bBv = g ? c : bBv; iB = g ? 4 * q + 2 : iB;
      c = tr[4 * q + 3] + dv.w; g = c > bBv; bBv = g ? c : bBv; iB = g ? 4 * q + 3 : iB;
    }
    bool gm = bBv > bA;  // tie -> lower half (first occurrence)
    psi[(size_t)r * kL + lane] = (unsigned char)(gm ? iB : iA);
  }
}

// ---------------- K3: segment composition (in-place psi -> M) ----------------
__global__ __launch_bounds__(256) void seg_compose(unsigned char* psiM,
                                                   unsigned char* __restrict__ C) {
  const int lane = threadIdx.x & 63;
  const int w = blockIdx.x * 4 + (threadIdx.x >> 6);
  const int s = w >> 7;
  const int b = w & 127;
  const int tstart = s * kSegLen;
  const int tend = (tstart + kSegLen < kT) ? tstart + kSegLen : kT - 1;  // last seg: 4095
  const size_t stride = (size_t)kB * kL;
  size_t off = ((size_t)(tend - 1) * kB + b) * kL + lane;
  int m = lane;
  int v = psiM[off];
  for (int t = tend - 1; t > tstart; --t) {
    int vn = psiM[off - stride];          // prefetch next row
    m = __shfl(v, m, 64);                 // m = psi_row[m]
    psiM[off] = (unsigned char)m;         // M[t][b][e] = path[t] | hyp e
    v = vn;
    off -= stride;
  }
  m = __shfl(v, m, 64);
  psiM[off] = (unsigned char)m;
  C[((size_t)s * kB + b) * kL + lane] = (unsigned char)m;  // composed map
}

// ---------------- K4: score, last label, boundary-label scan ----------------
__global__ __launch_bounds__(64) void score_scan(const float* __restrict__ dfin,
                                                 const unsigned char* __restrict__ C,
                                                 int* __restrict__ E,
                                                 float* __restrict__ out) {
  const int b = blockIdx.x;
  const int i = threadIdx.x;
  float d = dfin[(size_t)b * kL + i];
  float m = d;
#pragma unroll
  for (int off = 32; off; off >>= 1) m = fmaxf(m, __shfl_xor(m, off, 64));
  unsigned long long msk = __ballot(d == m);
  int ll = __ffsll(msk) - 1;  // first (lowest) argmax lane
  if (i == 0) {
    out[b] = m;
    out[kB + (size_t)b * kT + (kT - 1)] = (float)ll;
    int lbl = ll;
    for (int s = kSeg - 1; s >= 0; --s) {
      E[s * kB + b] = lbl;                              // label at t_end(s)
      lbl = C[((size_t)s * kB + b) * kL + lbl];         // -> label at t_start(s)
    }
  }
}

// ---------------- K5: parallel path gather ----------------
__global__ __launch_bounds__(256) void path_fill(const unsigned char* __restrict__ M,
                                                 const int* __restrict__ E,
                                                 float* __restrict__ out) {
  const int n = blockIdx.x * 256 + threadIdx.x;  // n = b*4096 + t
  const int b = n >> 12;
  const int t = n & (kT - 1);
  if (t == kT - 1) return;  // written by score_scan
  const int e = E[(t >> 6) * kB + b];
  const unsigned char lab = M[((size_t)t * kB + b) * kL + e];
  out[kB + (size_t)b * kT + t] = (float)lab;
}

extern "C" void kernel_launch(void* const* d_in, const int* in_sizes, int n_in,
                              void* d_out, int out_size, void* d_ws, size_t ws_size,
                              hipStream_t stream) {
  const float* feats = (const float*)d_in[0];
  const float* trans = (const float*)d_in[1];
  float* out = (float*)d_out;
  char* ws = (char*)d_ws;

  const size_t deltaB = (size_t)kT * kB * kL * 4;   // 134,217,728
  const size_t psiB   = (size_t)kT * kB * kL;       //  33,554,432
  const size_t CBy    = (size_t)kSeg * kB * kL;     //     524,288
  const size_t EBy    = (size_t)kSeg * kB * 4;      //      32,768

  if (ws_size >= deltaB + psiB + CBy + EBy) {
    // Plan A: value-only forward + fully-parallel backpointer recompute.
    float* delta = (float*)ws;
    unsigned char* psi = (unsigned char*)(ws + deltaB);
    unsigned char* C = (unsigned char*)(ws + deltaB + psiB);
    int* E = (int*)(ws + deltaB + psiB + CBy);
    hipLaunchKernelGGL(fwd_delta, dim3(kB), dim3(64), 0, stream, feats, trans, delta);
    hipLaunchKernelGGL(psi_from_delta, dim3(16380), dim3(256), 0, stream, delta, trans, psi);
    hipLaunchKernelGGL(seg_compose, dim3(2048), dim3(256), 0, stream, psi, C);
    hipLaunchKernelGGL(score_scan, dim3(kB), dim3(64), 0, stream,
                       delta + (size_t)(kT - 1) * kB * kL, C, E, out);
    hipLaunchKernelGGL(path_fill, dim3(2048), dim3(256), 0, stream, psi, E, out);
  } else {
    // Plan B: argmax in forward (psi only, ~34 MB workspace).
    unsigned char* psi = (unsigned char*)ws;
    unsigned char* C = (unsigned char*)(ws + psiB);
    int* E = (int*)(ws + psiB + CBy);
    float* dfin = (float*)(ws + psiB + CBy + EBy);
    hipLaunchKernelGGL(fwd_psi, dim3(kB), dim3(64), 0, stream, feats, trans, psi, dfin);
    hipLaunchKernelGGL(seg_compose, dim3(2048), dim3(256), 0, stream, psi, C);
    hipLaunchKernelGGL(score_scan, dim3(kB), dim3(64), 0, stream, dfin, C, E, out);
    hipLaunchKernelGGL(path_fill, dim3(2048), dim3(256), 0, stream, psi, E, out);
  }
}